// Round 10
// baseline (345.384 us; speedup 1.0000x reference)
//
#include <hip/hip_runtime.h>
#include <math.h>

#define BB 8
#define CC 64
#define HH 128
#define WW 128
#define EE 8
#define OO 64
#define HID 128
#define GATEC 96
#define NP 8     // patches per spatial dim
#define PP 16    // patch size

typedef __attribute__((ext_vector_type(8))) short bf16x8;
typedef __attribute__((ext_vector_type(4))) float f32x4;

static __device__ __forceinline__ unsigned short f2bf(float f) {
  unsigned int u = __builtin_bit_cast(unsigned int, f);
  unsigned int r = (u + 0x7FFFu + ((u >> 16) & 1u)) >> 16;   // RNE
  return (unsigned short)r;
}

// ---------------- Kernel A+P fused: router gates + weight pack ----------------
// blocks 0..511: gate (b*64 + pi*8 + pj); blocks 512..1663: pack
// pack layout: per tap (=e*9+t), 8 chunks of 512 halfwords (1 KB), chunk
// i = ks*4+ot; within a chunk lane l=(kg*16+px) holds its 8 contiguous
// halfwords -> each A-fragment load is ONE fully-coalesced 1 KB
// global_load_dwordx4 per wave:  elem (o,c):
//   dst = tap*4096 + ((c>>5)*4 + (o>>4))*512 + (((c>>3)&3)*16 + (o&15))*8 + (c&7)
__global__ __launch_bounds__(256) void prep_kernel(
    const float* __restrict__ x,
    const float* __restrict__ W1, const float* __restrict__ b1,
    const float* __restrict__ W2, const float* __restrict__ b2,
    const float* __restrict__ We,
    float* __restrict__ probs, unsigned short* __restrict__ wp) {
  __shared__ float ps[256];
  __shared__ float g[GATEC];
  __shared__ float hbuf[HID];
  __shared__ float lg[EE];

  if (blockIdx.x >= 512) {
    int idx = (blockIdx.x - 512) * 256 + threadIdx.x;
    if (idx < EE * 9 * OO * CC) {
      int c  = idx & 63;
      int o  = (idx >> 6) & 63;
      int et = idx >> 12;            // e*9 + t
      int t  = et % 9;
      int e  = et / 9;
      float v = We[(((size_t)(e * OO + o) * CC) + c) * 9 + t];
      int dst = (et << 12) + (((c >> 5) * 4 + (o >> 4)) << 9)
              + ((((c >> 3) & 3) * 16 + (o & 15)) << 3) + (c & 7);
      wp[dst] = f2bf(v);
    }
    return;
  }

  int blk = blockIdx.x;        // b*64 + pi*8 + pj
  int b  = blk >> 6;
  int pi = (blk >> 3) & 7;
  int pj = blk & 7;
  int t  = threadIdx.x;

  {
    int c = t >> 2, q = t & 3;
    const float* xb = x + ((size_t)(b * CC + c) * HH + pi * PP + q * 4) * WW + pj * PP;
    float s = 0.f;
    for (int r = 0; r < 4; ++r)
      for (int col = 0; col < PP; ++col)
        s += xb[r * WW + col];
    ps[t] = s;
  }
  __syncthreads();
  if (t < CC) {
    g[t] = (ps[4*t] + ps[4*t+1] + ps[4*t+2] + ps[4*t+3]) * (1.f / 256.f);
  } else if (t < CC + 32) {
    int k = t - CC;
    int fi = k & 7, kind = k >> 3;
    float freq  = (float)(1 << fi);
    float coord = (kind < 2) ? ((pi + 0.5f) / 8.f) : ((pj + 0.5f) / 8.f);
    float a = 6.28318530717958647692f * freq * coord;
    g[t] = (kind & 1) ? cosf(a) : sinf(a);
  }
  __syncthreads();
  if (t < HID) {
    float acc = b1[t];
    const float* w = W1 + (size_t)t * GATEC;
    for (int c = 0; c < GATEC; ++c) acc += w[c] * g[c];
    hbuf[t] = fmaxf(acc, 0.f);
  }
  __syncthreads();
  if (t < EE) {
    float acc = b2[t];
    const float* w = W2 + (size_t)t * HID;
    for (int k = 0; k < HID; ++k) acc += w[k] * hbuf[k];
    lg[t] = acc;
  }
  __syncthreads();
  if (t < EE) {
    float m = lg[0];
    for (int e = 1; e < EE; ++e) m = fmaxf(m, lg[e]);
    float sum = 0.f;
    for (int e = 0; e < EE; ++e) sum += expf(lg[e] - m);
    probs[((size_t)(b * EE + t) * NP + pi) * NP + pj] = expf(lg[t] - m) / sum;
  }
}

// ---------------- Kernel B: MFMA expert conv + gated combine ----------------
// block = (b, region 8 rows x 32 cols); 4 waves; wave = 64 o x (2 rows x 32 cols).
// Weights stream L2 -> registers (dual-bank, 1-tap-ahead prefetch), x in LDS.
// NEW vs R9: xs layout [c-chunk j][341][16B] (pad 341 -> distinct bank phases,
// NO xor swizzle) so every ds_read is base-reg + compile-time immediate;
// expert's 9 taps fully unrolled with constant (dy,dx); tap-0 MFMAs take C=0
// (no acc-reset movs). Main-loop VALU collapses to pointer bumps + epilogue.
__global__ __launch_bounds__(256, 2) void conv_moe(
    const float* __restrict__ x,
    const unsigned short* __restrict__ wp,   // packed [tap][8 x 1KB chunks] bf16
    const float* __restrict__ be,
    const float* __restrict__ probs, float* __restrict__ out) {
  int bx0 = blockIdx.x;            // rg*4 + cg
  int b   = blockIdx.y;
  int rg = bx0 >> 2, cg = bx0 & 3;
  const int h0 = rg * 8, w0 = cg * 32;
  const int pi = rg >> 1;          // patch row
  const int pj0 = cg * 2;          // left patch col

  int lane = threadIdx.x & 63;
  int wave = threadIdx.x >> 6;     // 0..3
  int px   = lane & 15;
  int kg   = lane >> 4;            // 0..3

  __shared__ char xs[8 * 341 * 16];   // [j][sp(340 used, pad 341)][16B]

  // ---- stage x tile (once): item = (j, sp=r*34+col) ----
  for (int i = 0; i < 11; ++i) {
    int idx = i * 256 + threadIdx.x;
    if (idx < 2720) {
      int j  = idx / 340;
      int sp = idx - j * 340;
      int r = sp / 34, col = sp - r * 34;
      int gr = h0 + r - 1, gc = w0 + col - 1;
      bf16x8 v;
      if (gr >= 0 && gr < HH && gc >= 0 && gc < WW) {
        const float* xb = x + ((size_t)(b * CC + j * 8) * HH + gr) * WW + gc;
#pragma unroll
        for (int q = 0; q < 8; ++q) v[q] = (short)f2bf(xb[(size_t)q * HH * WW]);
      } else {
#pragma unroll
        for (int q = 0; q < 8; ++q) v[q] = 0;
      }
      *(bf16x8*)(xs + (j * 341 + sp) * 16) = v;
    }
  }
  __syncthreads();   // ONLY barrier: xs read-only below

  // per-lane LDS base: chunk j = ks*4+kg, spatial (wave*2, px)
  const char* lb = xs + (kg * 341 + wave * 68 + px) * 16;
  // per-lane weight pointer: lane's 16B within each 1KB chunk
  const unsigned short* wq = wp + lane * 8;

  f32x4 outacc[16], acc[16];       // idx = ot*4 + f, f = rowp*2 + colhalf
#pragma unroll
  for (int i = 0; i < 16; ++i) outacc[i] = (f32x4)(0.f);
  const f32x4 kz = (f32x4)(0.f);

#define LOADW(bank, base, tap)                                                  \
  { _Pragma("unroll") for (int i_ = 0; i_ < 8; ++i_)                            \
      bank[i_] = *(const bf16x8*)((base) + (tap) * 4096 + i_ * 512); }

  // all-constant ds offset: [ks*4*341 + (rowp+dy)*34 + ch*16 + dx] * 16
#define LDSRD(ks, rd, ch, dx)                                                   \
  (*(const bf16x8*)(lb + ((ks) * 1364 + (rd) * 34 + (ch) * 16 + (dx)) * 16))

#define DOTAP(BANK, dy, dx, FIRST)                                              \
  {                                                                             \
    bf16x8 b0_[4], b1_[4];                                                      \
    _Pragma("unroll")                                                           \
    for (int f_ = 0; f_ < 4; ++f_) {                                            \
      const int rp_ = f_ >> 1, ch_ = f_ & 1;                                    \
      b0_[f_] = LDSRD(0, rp_ + (dy), ch_, (dx));                                \
      b1_[f_] = LDSRD(1, rp_ + (dy), ch_, (dx));                                \
    }                                                                           \
    __builtin_amdgcn_s_setprio(1);                                              \
    _Pragma("unroll")                                                           \
    for (int ot_ = 0; ot_ < 4; ++ot_)                                           \
      _Pragma("unroll")                                                         \
      for (int f_ = 0; f_ < 4; ++f_)                                            \
        acc[ot_ * 4 + f_] = __builtin_amdgcn_mfma_f32_16x16x32_bf16(            \
            BANK[ot_], b0_[f_], (FIRST) ? kz : acc[ot_ * 4 + f_], 0, 0, 0);     \
    _Pragma("unroll")                                                           \
    for (int ot_ = 0; ot_ < 4; ++ot_)                                           \
      _Pragma("unroll")                                                         \
      for (int f_ = 0; f_ < 4; ++f_)                                            \
        acc[ot_ * 4 + f_] = __builtin_amdgcn_mfma_f32_16x16x32_bf16(            \
            BANK[4 + ot_], b1_[f_], acc[ot_ * 4 + f_], 0, 0, 0);                \
    __builtin_amdgcn_s_setprio(0);                                              \
  }

#define EPILOGUE(eidx)                                                          \
  {                                                                             \
    float gA = probs[((size_t)(b * EE + (eidx)) * NP + pi) * NP + pj0];         \
    float gB = probs[((size_t)(b * EE + (eidx)) * NP + pi) * NP + pj0 + 1];     \
    _Pragma("unroll")                                                           \
    for (int ot_ = 0; ot_ < 4; ++ot_) {                                         \
      f32x4 bias = *(const f32x4*)(be + (eidx) * OO + ot_ * 16 + kg * 4);       \
      _Pragma("unroll")                                                         \
      for (int f_ = 0; f_ < 4; ++f_) {                                          \
        float gt = (f_ & 1) ? gB : gA;                                          \
        _Pragma("unroll")                                                       \
        for (int r_ = 0; r_ < 4; ++r_)                                          \
          outacc[ot_ * 4 + f_][r_] +=                                           \
              gt * fmaxf(acc[ot_ * 4 + f_][r_] + bias[r_], 0.f);                \
      }                                                                         \
    }                                                                           \
  }

  // taps (dy,dx) in row-major 3x3 order; banks alternate per tap; the trailing
  // LOADW pulls the NEXT expert's tap 0 so parity flips each expert.
#define EXPERT(eidx, B0, B1, wcur, wnext)                                       \
  {                                                                             \
    LOADW(B1, wcur, 1);  DOTAP(B0, 0, 0, true);                                 \
    LOADW(B0, wcur, 2);  DOTAP(B1, 0, 1, false);                                \
    LOADW(B1, wcur, 3);  DOTAP(B0, 0, 2, false);                                \
    LOADW(B0, wcur, 4);  DOTAP(B1, 1, 0, false);                                \
    LOADW(B1, wcur, 5);  DOTAP(B0, 1, 1, false);                                \
    LOADW(B0, wcur, 6);  DOTAP(B1, 1, 2, false);                                \
    LOADW(B1, wcur, 7);  DOTAP(B0, 2, 0, false);                                \
    LOADW(B0, wcur, 8);  DOTAP(B1, 2, 1, false);                                \
    LOADW(B1, wnext, 0); DOTAP(B0, 2, 2, false);                                \
    EPILOGUE(eidx);                                                             \
  }

  bf16x8 awA[8], awB[8];
  LOADW(awA, wq, 0);               // expert 0 tap 0

  const unsigned short* wqe = wq;
#pragma unroll 1
  for (int ep = 0; ep < 4; ++ep) {
    const unsigned short* wq1 = wqe + 9 * 4096;
    const unsigned short* wq2 = (ep == 3) ? wq : (wq1 + 9 * 4096);  // wrap: no OOB
    int e0 = ep * 2;
    EXPERT(e0,     awA, awB, wqe, wq1);
    EXPERT(e0 + 1, awB, awA, wq1, wq2);
    wqe = wq2;
  }

  // ---- store: lane holds o = ot*16+kg*4+r, col = w0 + ch*16 + px ----
#pragma unroll
  for (int ot = 0; ot < 4; ++ot) {
#pragma unroll
    for (int f = 0; f < 4; ++f) {
      int rowp = f >> 1, ch = f & 1;
      int o = ot * 16 + kg * 4;
      int h = h0 + wave * 2 + rowp;
      float* op = out + ((size_t)(b * OO + o) * HH + h) * WW + w0 + ch * 16 + px;
#pragma unroll
      for (int r = 0; r < 4; ++r)
        op[(size_t)r * HH * WW] = outacc[ot * 4 + f][r];
    }
  }
#undef LOADW
#undef LDSRD
#undef DOTAP
#undef EPILOGUE
#undef EXPERT
}

extern "C" void kernel_launch(void* const* d_in, const int* in_sizes, int n_in,
                              void* d_out, int out_size, void* d_ws, size_t ws_size,
                              hipStream_t stream) {
  const float* x  = (const float*)d_in[0];
  const float* We = (const float*)d_in[1];
  const float* be = (const float*)d_in[2];
  const float* W1 = (const float*)d_in[3];
  const float* b1 = (const float*)d_in[4];
  const float* W2 = (const float*)d_in[5];
  const float* b2 = (const float*)d_in[6];
  float* out = (float*)d_out;

  float* probs = (float*)d_ws;                                  // 16 KB
  unsigned short* wpk = (unsigned short*)((char*)d_ws + 16384); // 576 KB packed weights

  prep_kernel<<<dim3(512 + (EE * 9 * OO * CC + 255) / 256), dim3(256), 0, stream>>>(
      x, W1, b1, W2, b2, We, probs, wpk);
  conv_moe<<<dim3(16 * 4, BB), dim3(256), 0, stream>>>(x, wpk, be, probs, out);
}

// Round 11
// 98.731 us; speedup vs baseline: 3.4982x; 3.4982x over previous
//
#include <hip/hip_runtime.h>
#include <math.h>

#define BB 8
#define CC 64
#define HH 128
#define WW 128
#define EE 8
#define OO 64
#define HID 128
#define GATEC 96
#define NP 8     // patches per spatial dim
#define PP 16    // patch size

typedef __attribute__((ext_vector_type(8))) short bf16x8;
typedef __attribute__((ext_vector_type(4))) float f32x4;

static __device__ __forceinline__ unsigned short f2bf(float f) {
  unsigned int u = __builtin_bit_cast(unsigned int, f);
  unsigned int r = (u + 0x7FFFu + ((u >> 16) & 1u)) >> 16;   // RNE
  return (unsigned short)r;
}

// ---------------- Kernel A+P fused: router gates + weight pack ----------------
// blocks 0..511: gate (b*64 + pi*8 + pj); blocks 512..1663: pack
// pack layout: per tap (=e*9+t), 8 chunks of 512 halfwords (1 KB), chunk
// i = ks*4+ot; within a chunk lane l=(kg*16+px) holds its 8 contiguous
// halfwords -> each A-fragment load is ONE fully-coalesced 1 KB load:
//   dst = tap*4096 + ((c>>5)*4 + (o>>4))*512 + (((c>>3)&3)*16 + (o&15))*8 + (c&7)
__global__ __launch_bounds__(256) void prep_kernel(
    const float* __restrict__ x,
    const float* __restrict__ W1, const float* __restrict__ b1,
    const float* __restrict__ W2, const float* __restrict__ b2,
    const float* __restrict__ We,
    float* __restrict__ probs, unsigned short* __restrict__ wp) {
  __shared__ float ps[256];
  __shared__ float g[GATEC];
  __shared__ float hbuf[HID];
  __shared__ float lg[EE];

  if (blockIdx.x >= 512) {
    int idx = (blockIdx.x - 512) * 256 + threadIdx.x;
    if (idx < EE * 9 * OO * CC) {
      int c  = idx & 63;
      int o  = (idx >> 6) & 63;
      int et = idx >> 12;            // e*9 + t
      int t  = et % 9;
      int e  = et / 9;
      float v = We[(((size_t)(e * OO + o) * CC) + c) * 9 + t];
      int dst = (et << 12) + (((c >> 5) * 4 + (o >> 4)) << 9)
              + ((((c >> 3) & 3) * 16 + (o & 15)) << 3) + (c & 7);
      wp[dst] = f2bf(v);
    }
    return;
  }

  int blk = blockIdx.x;        // b*64 + pi*8 + pj
  int b  = blk >> 6;
  int pi = (blk >> 3) & 7;
  int pj = blk & 7;
  int t  = threadIdx.x;

  {
    int c = t >> 2, q = t & 3;
    const float* xb = x + ((size_t)(b * CC + c) * HH + pi * PP + q * 4) * WW + pj * PP;
    float s = 0.f;
    for (int r = 0; r < 4; ++r)
      for (int col = 0; col < PP; ++col)
        s += xb[r * WW + col];
    ps[t] = s;
  }
  __syncthreads();
  if (t < CC) {
    g[t] = (ps[4*t] + ps[4*t+1] + ps[4*t+2] + ps[4*t+3]) * (1.f / 256.f);
  } else if (t < CC + 32) {
    int k = t - CC;
    int fi = k & 7, kind = k >> 3;
    float freq  = (float)(1 << fi);
    float coord = (kind < 2) ? ((pi + 0.5f) / 8.f) : ((pj + 0.5f) / 8.f);
    float a = 6.28318530717958647692f * freq * coord;
    g[t] = (kind & 1) ? cosf(a) : sinf(a);
  }
  __syncthreads();
  if (t < HID) {
    float acc = b1[t];
    const float* w = W1 + (size_t)t * GATEC;
    for (int c = 0; c < GATEC; ++c) acc += w[c] * g[c];
    hbuf[t] = fmaxf(acc, 0.f);
  }
  __syncthreads();
  if (t < EE) {
    float acc = b2[t];
    const float* w = W2 + (size_t)t * HID;
    for (int k = 0; k < HID; ++k) acc += w[k] * hbuf[k];
    lg[t] = acc;
  }
  __syncthreads();
  if (t < EE) {
    float m = lg[0];
    for (int e = 1; e < EE; ++e) m = fmaxf(m, lg[e]);
    float sum = 0.f;
    for (int e = 0; e < EE; ++e) sum += expf(lg[e] - m);
    probs[((size_t)(b * EE + t) * NP + pi) * NP + pj] = expf(lg[t] - m) / sum;
  }
}

// ---------------- Kernel B: MFMA expert conv + gated combine ----------------
// block = (b, region 8 rows x 32 cols); 4 waves; wave = 64 o x (2 rows x 32 cols).
// Weights stream L2 -> registers (dual-bank, 1-tap-ahead prefetch), x in LDS.
// = R9 structure (83us known-good: small body, 2 banks, runtime bookkeeping)
// + R10's padded [j][341][16B] xs layout WITHOUT the unroll: ds_read address is
// per-lane base + wave-uniform SGPR `off` (maintained incrementally) + constant
// immediates. Kills the per-read XOR chains (~48 VALU/tap -> ~3).
__global__ __launch_bounds__(256, 2) void conv_moe(
    const float* __restrict__ x,
    const unsigned short* __restrict__ wp,   // packed [tap][8 x 1KB chunks] bf16
    const float* __restrict__ be,
    const float* __restrict__ probs, float* __restrict__ out) {
  int bx0 = blockIdx.x;            // rg*4 + cg
  int b   = blockIdx.y;
  int rg = bx0 >> 2, cg = bx0 & 3;
  const int h0 = rg * 8, w0 = cg * 32;
  const int pi = rg >> 1;          // patch row
  const int pj0 = cg * 2;          // left patch col

  int lane = threadIdx.x & 63;
  int wave = threadIdx.x >> 6;     // 0..3
  int px   = lane & 15;
  int kg   = lane >> 4;            // 0..3

  __shared__ char xs[8 * 341 * 16];   // [j][sp(340 used, pad 341)][16B]

  // ---- stage x tile (once): item = (j, sp=r*34+col) ----
  for (int i = 0; i < 11; ++i) {
    int idx = i * 256 + threadIdx.x;
    if (idx < 2720) {
      int j  = idx / 340;
      int sp = idx - j * 340;
      int r = sp / 34, col = sp - r * 34;
      int gr = h0 + r - 1, gc = w0 + col - 1;
      bf16x8 v;
      if (gr >= 0 && gr < HH && gc >= 0 && gc < WW) {
        const float* xb = x + ((size_t)(b * CC + j * 8) * HH + gr) * WW + gc;
#pragma unroll
        for (int q = 0; q < 8; ++q) v[q] = (short)f2bf(xb[(size_t)q * HH * WW]);
      } else {
#pragma unroll
        for (int q = 0; q < 8; ++q) v[q] = 0;
      }
      *(bf16x8*)(xs + (j * 341 + sp) * 16) = v;
    }
  }
  __syncthreads();   // ONLY barrier: xs read-only below

  // per-lane LDS base: chunk j = ks*4+kg, spatial (wave*2 rows, px)
  const char* lb = xs + (kg * 341 + wave * 68 + px) * 16;
  // per-lane weight pointer: lane's 16B within each 1KB chunk
  const unsigned short* wq = wp + lane * 8;

  f32x4 outacc[4][4], acc[4][4];   // [ot][f = rowp*2 + colhalf]
#pragma unroll
  for (int ot = 0; ot < 4; ++ot)
#pragma unroll
    for (int f = 0; f < 4; ++f) { outacc[ot][f] = (f32x4)(0.f); acc[ot][f] = (f32x4)(0.f); }

#define LOADW(bank, tap)                                                        \
  { _Pragma("unroll") for (int i_ = 0; i_ < 8; ++i_)                            \
      bank[i_] = *(const bf16x8*)(wq + (size_t)(tap) * 4096 + i_ * 512); }

  // ds addr = lb + off(tap, SGPR) + const[ks*1364 + rowp*34 + ch*16]*16
#define TAP(BANK, off)                                                          \
  {                                                                             \
    const char* ta = lb + (off);                                                \
    bf16x8 b0_[4], b1_[4];                                                      \
    _Pragma("unroll")                                                           \
    for (int f_ = 0; f_ < 4; ++f_) {                                            \
      const int rp_ = f_ >> 1, ch_ = f_ & 1;                                    \
      b0_[f_] = *(const bf16x8*)(ta + (rp_ * 34 + ch_ * 16) * 16);              \
      b1_[f_] = *(const bf16x8*)(ta + (1364 + rp_ * 34 + ch_ * 16) * 16);       \
    }                                                                           \
    __builtin_amdgcn_s_setprio(1);                                              \
    _Pragma("unroll")                                                           \
    for (int ot_ = 0; ot_ < 4; ++ot_)                                           \
      _Pragma("unroll")                                                         \
      for (int f_ = 0; f_ < 4; ++f_)                                            \
        acc[ot_][f_] = __builtin_amdgcn_mfma_f32_16x16x32_bf16(                 \
            BANK[ot_], b0_[f_], acc[ot_][f_], 0, 0, 0);                         \
    _Pragma("unroll")                                                           \
    for (int ot_ = 0; ot_ < 4; ++ot_)                                           \
      _Pragma("unroll")                                                         \
      for (int f_ = 0; f_ < 4; ++f_)                                            \
        acc[ot_][f_] = __builtin_amdgcn_mfma_f32_16x16x32_bf16(                 \
            BANK[4 + ot_], b1_[f_], acc[ot_][f_], 0, 0, 0);                     \
    __builtin_amdgcn_s_setprio(0);                                              \
  }

#define EPILOGUE(eidx)                                                          \
  {                                                                             \
    float gA = probs[((size_t)(b * EE + (eidx)) * NP + pi) * NP + pj0];         \
    float gB = probs[((size_t)(b * EE + (eidx)) * NP + pi) * NP + pj0 + 1];     \
    _Pragma("unroll")                                                           \
    for (int ot_ = 0; ot_ < 4; ++ot_) {                                         \
      f32x4 bias = *(const f32x4*)(be + (eidx) * OO + ot_ * 16 + kg * 4);       \
      _Pragma("unroll")                                                         \
      for (int f_ = 0; f_ < 4; ++f_) {                                          \
        float gt = (f_ & 1) ? gB : gA;                                          \
        _Pragma("unroll")                                                       \
        for (int r_ = 0; r_ < 4; ++r_) {                                        \
          outacc[ot_][f_][r_] += gt * fmaxf(acc[ot_][f_][r_] + bias[r_], 0.f);  \
          acc[ot_][f_][r_] = 0.f;                                               \
        }                                                                       \
      }                                                                         \
    }                                                                           \
  }

  // off advance over taps (row-major 3x3): dx++ -> +16B*1? no: +1 col = +16B;
  // dy++ (dx wrap) -> +32*16B (34-2 cols back) ... all wave-uniform (SGPR).
#define ADVANCE()                                                               \
  {                                                                             \
    if (t9 == 8) { EPILOGUE(e); ++e; t9 = 0; dx = 0; off = 0; }                 \
    else { ++t9; if (++dx == 3) { dx = 0; off += 512; } else { off += 16; } }   \
  }

  bf16x8 awA[8], awB[8];
  LOADW(awA, 0);
  LOADW(awB, 1);

  int e = 0, t9 = 0, dx = 0, off = 0;
#pragma unroll 1
  for (int u = 0; u < 36; ++u) {
    TAP(awA, off);
    if (u < 35) LOADW(awA, 2 * u + 2);
    ADVANCE();
    TAP(awB, off);
    if (u < 35) LOADW(awB, 2 * u + 3);
    ADVANCE();
  }

  // ---- store: lane holds o = ot*16+kg*4+r, col = w0 + ch*16 + px ----
#pragma unroll
  for (int ot = 0; ot < 4; ++ot) {
#pragma unroll
    for (int f = 0; f < 4; ++f) {
      int rowp = f >> 1, ch = f & 1;
      int o = ot * 16 + kg * 4;
      int h = h0 + wave * 2 + rowp;
      float* op = out + ((size_t)(b * OO + o) * HH + h) * WW + w0 + ch * 16 + px;
#pragma unroll
      for (int r = 0; r < 4; ++r)
        op[(size_t)r * HH * WW] = outacc[ot][f][r];
    }
  }
#undef LOADW
#undef TAP
#undef EPILOGUE
#undef ADVANCE
}

extern "C" void kernel_launch(void* const* d_in, const int* in_sizes, int n_in,
                              void* d_out, int out_size, void* d_ws, size_t ws_size,
                              hipStream_t stream) {
  const float* x  = (const float*)d_in[0];
  const float* We = (const float*)d_in[1];
  const float* be = (const float*)d_in[2];
  const float* W1 = (const float*)d_in[3];
  const float* b1 = (const float*)d_in[4];
  const float* W2 = (const float*)d_in[5];
  const float* b2 = (const float*)d_in[6];
  float* out = (float*)d_out;

  float* probs = (float*)d_ws;                                  // 16 KB
  unsigned short* wpk = (unsigned short*)((char*)d_ws + 16384); // 576 KB packed weights

  prep_kernel<<<dim3(512 + (EE * 9 * OO * CC + 255) / 256), dim3(256), 0, stream>>>(
      x, W1, b1, W2, b2, We, probs, wpk);
  conv_moe<<<dim3(16 * 4, BB), dim3(256), 0, stream>>>(x, wpk, be, probs, out);
}

// Round 12
// 97.863 us; speedup vs baseline: 3.5293x; 1.0089x over previous
//
#include <hip/hip_runtime.h>
#include <math.h>

#define BB 8
#define CC 64
#define HH 128
#define WW 128
#define EE 8
#define OO 64
#define HID 128
#define GATEC 96
#define NP 8     // patches per spatial dim
#define PP 16    // patch size

typedef __attribute__((ext_vector_type(8))) short bf16x8;
typedef __attribute__((ext_vector_type(4))) float f32x4;

static __device__ __forceinline__ unsigned short f2bf(float f) {
  unsigned int u = __builtin_bit_cast(unsigned int, f);
  unsigned int r = (u + 0x7FFFu + ((u >> 16) & 1u)) >> 16;   // RNE
  return (unsigned short)r;
}

// ---------------- Kernel A+P fused: router gates + weight pack ----------------
// blocks 0..511: gate (b*64 + pi*8 + pj); blocks 512..639: pack
// pack layout: per tap (=e*9+t), 8 chunks of 512 halfwords (1 KB), chunk
// i = ks*4+ot; within a chunk lane l=(kg*16+px) holds its 8 contiguous
// halfwords -> each A-fragment load is ONE fully-coalesced 1 KB load:
//   dst = tap*4096 + ((c>>5)*4 + (o>>4))*512 + (((c>>3)&3)*16 + (o&15))*8 + (c&7)
// NEW vs R11: pack is thread-per-(e,o,c) reading 9 CONTIGUOUS floats (the
// [o][c][3][3] innermost taps) -> fully coalesced 2.3 MB read instead of
// stride-9 gathers (9x overfetch). Gate pooling reads f32x4.
__global__ __launch_bounds__(256) void prep_kernel(
    const float* __restrict__ x,
    const float* __restrict__ W1, const float* __restrict__ b1,
    const float* __restrict__ W2, const float* __restrict__ b2,
    const float* __restrict__ We,
    float* __restrict__ probs, unsigned short* __restrict__ wp) {
  __shared__ float ps[256];
  __shared__ float g[GATEC];
  __shared__ float hbuf[HID];
  __shared__ float lg[EE];

  if (blockIdx.x >= 512) {
    int idx = (blockIdx.x - 512) * 256 + threadIdx.x;   // (e*64+o)*64+c
    if (idx < EE * OO * CC) {
      int c = idx & 63;
      int o = (idx >> 6) & 63;
      int e = idx >> 12;
      const float* src = We + (size_t)idx * 9;          // 9 contiguous taps
      float v[9];
#pragma unroll
      for (int t = 0; t < 9; ++t) v[t] = src[t];
      int base = (((c >> 5) * 4 + (o >> 4)) << 9)
               + ((((c >> 3) & 3) * 16 + (o & 15)) << 3) + (c & 7);
#pragma unroll
      for (int t = 0; t < 9; ++t) {
        int et = e * 9 + t;
        wp[(et << 12) + base] = f2bf(v[t]);
      }
    }
    return;
  }

  int blk = blockIdx.x;        // b*64 + pi*8 + pj
  int b  = blk >> 6;
  int pi = (blk >> 3) & 7;
  int pj = blk & 7;
  int t  = threadIdx.x;

  {
    int c = t >> 2, q = t & 3;
    const f32x4* xb = (const f32x4*)(x + ((size_t)(b * CC + c) * HH + pi * PP + q * 4) * WW + pj * PP);
    float s = 0.f;
    for (int r = 0; r < 4; ++r) {
#pragma unroll
      for (int v4 = 0; v4 < 4; ++v4) {
        f32x4 w = xb[r * (WW / 4) + v4];
        s += w[0] + w[1] + w[2] + w[3];
      }
    }
    ps[t] = s;
  }
  __syncthreads();
  if (t < CC) {
    g[t] = (ps[4*t] + ps[4*t+1] + ps[4*t+2] + ps[4*t+3]) * (1.f / 256.f);
  } else if (t < CC + 32) {
    int k = t - CC;
    int fi = k & 7, kind = k >> 3;
    float freq  = (float)(1 << fi);
    float coord = (kind < 2) ? ((pi + 0.5f) / 8.f) : ((pj + 0.5f) / 8.f);
    float a = 6.28318530717958647692f * freq * coord;
    g[t] = (kind & 1) ? cosf(a) : sinf(a);
  }
  __syncthreads();
  if (t < HID) {
    float acc = b1[t];
    const float* w = W1 + (size_t)t * GATEC;
    for (int c = 0; c < GATEC; ++c) acc += w[c] * g[c];
    hbuf[t] = fmaxf(acc, 0.f);
  }
  __syncthreads();
  if (t < EE) {
    float acc = b2[t];
    const float* w = W2 + (size_t)t * HID;
    for (int k = 0; k < HID; ++k) acc += w[k] * hbuf[k];
    lg[t] = acc;
  }
  __syncthreads();
  if (t < EE) {
    float m = lg[0];
    for (int e = 1; e < EE; ++e) m = fmaxf(m, lg[e]);
    float sum = 0.f;
    for (int e = 0; e < EE; ++e) sum += expf(lg[e] - m);
    probs[((size_t)(b * EE + t) * NP + pi) * NP + pj] = expf(lg[t] - m) / sum;
  }
}

// ---------------- Kernel B: MFMA expert conv + gated combine ----------------
// UNCHANGED from R11 (83.4 us, 931 TF = m97-structure ceiling for M=64).
// block = (b, region 8 rows x 32 cols); 4 waves; wave = 64 o x (2 rows x 32 cols).
// Weights stream L2 -> registers (dual-bank, 1-tap-ahead prefetch), x in LDS
// padded [j][341][16B]; ds_read = per-lane base + wave-uniform SGPR off +
// constant immediates; no main-loop barriers.
__global__ __launch_bounds__(256, 2) void conv_moe(
    const float* __restrict__ x,
    const unsigned short* __restrict__ wp,   // packed [tap][8 x 1KB chunks] bf16
    const float* __restrict__ be,
    const float* __restrict__ probs, float* __restrict__ out) {
  int bx0 = blockIdx.x;            // rg*4 + cg
  int b   = blockIdx.y;
  int rg = bx0 >> 2, cg = bx0 & 3;
  const int h0 = rg * 8, w0 = cg * 32;
  const int pi = rg >> 1;          // patch row
  const int pj0 = cg * 2;          // left patch col

  int lane = threadIdx.x & 63;
  int wave = threadIdx.x >> 6;     // 0..3
  int px   = lane & 15;
  int kg   = lane >> 4;            // 0..3

  __shared__ char xs[8 * 341 * 16];   // [j][sp(340 used, pad 341)][16B]

  // ---- stage x tile (once): item = (j, sp=r*34+col) ----
  for (int i = 0; i < 11; ++i) {
    int idx = i * 256 + threadIdx.x;
    if (idx < 2720) {
      int j  = idx / 340;
      int sp = idx - j * 340;
      int r = sp / 34, col = sp - r * 34;
      int gr = h0 + r - 1, gc = w0 + col - 1;
      bf16x8 v;
      if (gr >= 0 && gr < HH && gc >= 0 && gc < WW) {
        const float* xb = x + ((size_t)(b * CC + j * 8) * HH + gr) * WW + gc;
#pragma unroll
        for (int q = 0; q < 8; ++q) v[q] = (short)f2bf(xb[(size_t)q * HH * WW]);
      } else {
#pragma unroll
        for (int q = 0; q < 8; ++q) v[q] = 0;
      }
      *(bf16x8*)(xs + (j * 341 + sp) * 16) = v;
    }
  }
  __syncthreads();   // ONLY barrier: xs read-only below

  // per-lane LDS base: chunk j = ks*4+kg, spatial (wave*2 rows, px)
  const char* lb = xs + (kg * 341 + wave * 68 + px) * 16;
  // per-lane weight pointer: lane's 16B within each 1KB chunk
  const unsigned short* wq = wp + lane * 8;

  f32x4 outacc[4][4], acc[4][4];   // [ot][f = rowp*2 + colhalf]
#pragma unroll
  for (int ot = 0; ot < 4; ++ot)
#pragma unroll
    for (int f = 0; f < 4; ++f) { outacc[ot][f] = (f32x4)(0.f); acc[ot][f] = (f32x4)(0.f); }

#define LOADW(bank, tap)                                                        \
  { _Pragma("unroll") for (int i_ = 0; i_ < 8; ++i_)                            \
      bank[i_] = *(const bf16x8*)(wq + (size_t)(tap) * 4096 + i_ * 512); }

  // ds addr = lb + off(tap, SGPR) + const[ks*1364 + rowp*34 + ch*16]*16
#define TAP(BANK, off)                                                          \
  {                                                                             \
    const char* ta = lb + (off);                                                \
    bf16x8 b0_[4], b1_[4];                                                      \
    _Pragma("unroll")                                                           \
    for (int f_ = 0; f_ < 4; ++f_) {                                            \
      const int rp_ = f_ >> 1, ch_ = f_ & 1;                                    \
      b0_[f_] = *(const bf16x8*)(ta + (rp_ * 34 + ch_ * 16) * 16);              \
      b1_[f_] = *(const bf16x8*)(ta + (1364 + rp_ * 34 + ch_ * 16) * 16);       \
    }                                                                           \
    __builtin_amdgcn_s_setprio(1);                                              \
    _Pragma("unroll")                                                           \
    for (int ot_ = 0; ot_ < 4; ++ot_)                                           \
      _Pragma("unroll")                                                         \
      for (int f_ = 0; f_ < 4; ++f_)                                            \
        acc[ot_][f_] = __builtin_amdgcn_mfma_f32_16x16x32_bf16(                 \
            BANK[ot_], b0_[f_], acc[ot_][f_], 0, 0, 0);                         \
    _Pragma("unroll")                                                           \
    for (int ot_ = 0; ot_ < 4; ++ot_)                                           \
      _Pragma("unroll")                                                         \
      for (int f_ = 0; f_ < 4; ++f_)                                            \
        acc[ot_][f_] = __builtin_amdgcn_mfma_f32_16x16x32_bf16(                 \
            BANK[4 + ot_], b1_[f_], acc[ot_][f_], 0, 0, 0);                     \
    __builtin_amdgcn_s_setprio(0);                                              \
  }

#define EPILOGUE(eidx)                                                          \
  {                                                                             \
    float gA = probs[((size_t)(b * EE + (eidx)) * NP + pi) * NP + pj0];         \
    float gB = probs[((size_t)(b * EE + (eidx)) * NP + pi) * NP + pj0 + 1];     \
    _Pragma("unroll")                                                           \
    for (int ot_ = 0; ot_ < 4; ++ot_) {                                         \
      f32x4 bias = *(const f32x4*)(be + (eidx) * OO + ot_ * 16 + kg * 4);       \
      _Pragma("unroll")                                                         \
      for (int f_ = 0; f_ < 4; ++f_) {                                          \
        float gt = (f_ & 1) ? gB : gA;                                          \
        _Pragma("unroll")                                                       \
        for (int r_ = 0; r_ < 4; ++r_) {                                        \
          outacc[ot_][f_][r_] += gt * fmaxf(acc[ot_][f_][r_] + bias[r_], 0.f);  \
          acc[ot_][f_][r_] = 0.f;                                               \
        }                                                                       \
      }                                                                         \
    }                                                                           \
  }

#define ADVANCE()                                                               \
  {                                                                             \
    if (t9 == 8) { EPILOGUE(e); ++e; t9 = 0; dx = 0; off = 0; }                 \
    else { ++t9; if (++dx == 3) { dx = 0; off += 512; } else { off += 16; } }   \
  }

  bf16x8 awA[8], awB[8];
  LOADW(awA, 0);
  LOADW(awB, 1);

  int e = 0, t9 = 0, dx = 0, off = 0;
#pragma unroll 1
  for (int u = 0; u < 36; ++u) {
    TAP(awA, off);
    if (u < 35) LOADW(awA, 2 * u + 2);
    ADVANCE();
    TAP(awB, off);
    if (u < 35) LOADW(awB, 2 * u + 3);
    ADVANCE();
  }

  // ---- store: lane holds o = ot*16+kg*4+r, col = w0 + ch*16 + px ----
#pragma unroll
  for (int ot = 0; ot < 4; ++ot) {
#pragma unroll
    for (int f = 0; f < 4; ++f) {
      int rowp = f >> 1, ch = f & 1;
      int o = ot * 16 + kg * 4;
      int h = h0 + wave * 2 + rowp;
      float* op = out + ((size_t)(b * OO + o) * HH + h) * WW + w0 + ch * 16 + px;
#pragma unroll
      for (int r = 0; r < 4; ++r)
        op[(size_t)r * HH * WW] = outacc[ot][f][r];
    }
  }
#undef LOADW
#undef TAP
#undef EPILOGUE
#undef ADVANCE
}

extern "C" void kernel_launch(void* const* d_in, const int* in_sizes, int n_in,
                              void* d_out, int out_size, void* d_ws, size_t ws_size,
                              hipStream_t stream) {
  const float* x  = (const float*)d_in[0];
  const float* We = (const float*)d_in[1];
  const float* be = (const float*)d_in[2];
  const float* W1 = (const float*)d_in[3];
  const float* b1 = (const float*)d_in[4];
  const float* W2 = (const float*)d_in[5];
  const float* b2 = (const float*)d_in[6];
  float* out = (float*)d_out;

  float* probs = (float*)d_ws;                                  // 16 KB
  unsigned short* wpk = (unsigned short*)((char*)d_ws + 16384); // 576 KB packed weights

  prep_kernel<<<dim3(512 + (EE * OO * CC + 255) / 256), dim3(256), 0, stream>>>(
      x, W1, b1, W2, b2, We, probs, wpk);
  conv_moe<<<dim3(16 * 4, BB), dim3(256), 0, stream>>>(x, wpk, be, probs, out);
}